// Round 6
// baseline (1301.503 us; speedup 1.0000x reference)
//
#include <hip/hip_runtime.h>

typedef unsigned short u16;
typedef unsigned int   u32;
typedef __attribute__((ext_vector_type(4)))  float f32x4;
typedef __attribute__((ext_vector_type(16))) float f32x16;
typedef __attribute__((ext_vector_type(8)))  short b16x8;

#define T_ 256
#define B_ 32
#define V_ 32000
#define H_ 256

// fp32 -> bf16 round-to-nearest-even (verified path, rounds 1-4)
__device__ __forceinline__ u16 f2bf(float f){
  union { float fv; u32 uv; } v; v.fv = f;
  return (u16)((v.uv + 0x7FFFu + ((v.uv >> 16) & 1u)) >> 16);
}
__device__ __forceinline__ float bf2f(short x){
  union { float fv; u32 uv; } c; c.uv = ((u32)(u16)x) << 16; return c.fv;
}
__device__ __forceinline__ float sigm_fast(float z){
  return __builtin_amdgcn_rcpf(1.0f + __builtin_amdgcn_exp2f(z * -1.44269504f));
}

// ---------------------------------------------------------------------------
// prep: decW -> bf16 ; W^T bf16 copies (WhT0, WiT1, WhT1, WiT0)
// ---------------------------------------------------------------------------
__global__ __launch_bounds__(256)
void prep_kernel(const float* __restrict__ Wi, const float* __restrict__ Wh,
                 const float* __restrict__ decW,
                 u16* __restrict__ decWb, u16* __restrict__ wt){
  const int NDEC = V_ * H_;
  const int NWT  = 4 * H_ * H_;
  const int total = NDEC + NWT;
  for (int i = blockIdx.x * blockDim.x + threadIdx.x; i < total;
       i += gridDim.x * blockDim.x){
    if (i < NDEC){
      decWb[i] = f2bf(decW[i]);
    } else {
      int j = i - NDEC;
      int m = j >> 16;
      int r = j & 65535;
      int row = r >> 8;
      int k   = r & 255;
      const float* src = (m == 0) ? Wh
                       : (m == 1) ? (Wi + H_ * H_)
                       : (m == 2) ? (Wh + H_ * H_)
                       :            Wi;
      wt[j] = f2bf(src[k * H_ + row]);
    }
  }
}

// Permuted x layout for the 32x32x16 rec consumer:
//   slab element (row = q*8 + hi*4 + r2, col) of step t lives at
//   xp[t*8192 + ((q*2+hi)*256 + col)*4 + r2]

// ---------------------------------------------------------------------------
// x0[t][b][j] = bh0[j] + emb[ids[t,b]] @ Wi0   (permuted store)
// ---------------------------------------------------------------------------
__global__ __launch_bounds__(512, 2)
void x0_kernel(const int* __restrict__ ids, const float* __restrict__ emb,
               const u16* __restrict__ WiT0, const float* __restrict__ bh,
               float* __restrict__ xp){
  const int tid = threadIdx.x, w = tid >> 6, l = tid & 63, lr = l & 15, lh = l >> 4;
  const int mb = blockIdx.x >> 2;
  const int nb = blockIdx.x & 3;
  const int arow = mb * 128 + w * 16 + lr;
  const int id = ids[arow];
  const float* erow = emb + (size_t)id * H_;

  f32x4 acc[4];
  #pragma unroll
  for (int nt = 0; nt < 4; ++nt){
    float b0 = bh[nb * 64 + nt * 16 + lr];
    acc[nt] = (f32x4){b0, b0, b0, b0};
  }
  #pragma unroll
  for (int ks = 0; ks < 8; ++ks){
    const float* ap = erow + ks * 32 + lh * 8;
    f32x4 e0 = *(const f32x4*)(ap);
    f32x4 e1 = *(const f32x4*)(ap + 4);
    b16x8 a;
    #pragma unroll
    for (int i2 = 0; i2 < 4; ++i2){
      a[i2]     = (short)f2bf(e0[i2]);
      a[4 + i2] = (short)f2bf(e1[i2]);
    }
    #pragma unroll
    for (int nt = 0; nt < 4; ++nt){
      b16x8 b = *(const b16x8*)(WiT0 + (size_t)(nb * 64 + nt * 16 + lr) * H_ + ks * 32 + lh * 8);
      acc[nt] = __builtin_amdgcn_mfma_f32_16x16x32_bf16(a, b, acc[nt], 0, 0, 0);
    }
  }
  const int t   = mb * 4 + (w >> 1);
  const int q   = (w & 1) * 2 + (lh >> 1);
  const int hi2 = lh & 1;
  #pragma unroll
  for (int nt = 0; nt < 4; ++nt){
    const int col = nb * 64 + nt * 16 + lr;
    *(f32x4*)(xp + (size_t)t * 8192 + ((q * 2 + hi2) * 256 + col) * 4) = acc[nt];
  }
}

// ---------------------------------------------------------------------------
// fused_rec: BOTH layers, one block, 8 waves, one barrier/step.
// Step s (s=0..255), PAR = s&1:
//   A: store outseq[s-2] = h1[s-2]   (from h1b[1-PAR], lag-2)
//   B: c = x0[s](C-init) + h0[s-1]@Wh0 ; d = b1(splat) + h0[s-1]@Wi1
//      (shared A-fragment LDS reads feed both chains)
//   C: prefetch x0[s+1] into regs
//   D: h0[s] = sigm(c) -> h0b[1-PAR]
//   E: d += h1[s-2]@Wh1                (Wh1 streamed from L2, 8+8 frags)
//   F: h1[s-1] = sigm(d) -> h1b[PAR]   (s>=1)
// Invariant: h0[u] in h0b[(u+1)&1]; h1[u] in h1b[(u+1)&1].
// LDS layout: byte(row,col) = row*512 + ((col*2) ^ ((row&7)<<4))
// ---------------------------------------------------------------------------
__global__ __launch_bounds__(512, 1)
void fused_rec(const u16* __restrict__ wt, const float* __restrict__ xp,
               const float* __restrict__ bh,
               u16* __restrict__ outseq, float* __restrict__ hid){
  __shared__ u16 h0b[2][B_ * H_];                     // 2 x 16 KiB
  __shared__ u16 h1b[2][B_ * H_];                     // 2 x 16 KiB
  const int tid = threadIdx.x, w = tid >> 6, l = tid & 63;
  const int la = l & 31, hi = l >> 5, p = la & 7;
  const int col = w * 32 + la;

  const u16* whT0 = wt;
  const u16* wiT1 = wt + 65536;

  // persistent weights: Wh0, Wi1 (128 VGPR)
  b16x8 wH0[16], wI1[16];
  #pragma unroll
  for (int ks = 0; ks < 16; ++ks){
    wH0[ks] = *(const b16x8*)(whT0 + (size_t)col * H_ + ks * 16 + hi * 8);
    wI1[ks] = *(const b16x8*)(wiT1 + (size_t)col * H_ + ks * 16 + hi * 8);
  }
  const u16* wh1p = wt + 131072 + (size_t)col * H_ + hi * 8;  // Wh1 stream base
  const float b1 = bh[H_ + col];

  // A-read bases: addr(k) = base4[k&3] + (k>>2)*128
  int base4[4];
  #pragma unroll
  for (int m = 0; m < 4; ++m)
    base4[m] = la * 512 + (((m * 2 + hi) ^ p) << 4);

  // h-write offsets: byte = q*4096 + wa[r2]
  int wa[4];
  #pragma unroll
  for (int r2 = 0; r2 < 4; ++r2)
    wa[r2] = hi * 2048 + r2 * 512 + ((col * 2) ^ ((hi * 4 + r2) << 4));

  // linear store-read addrs (element e = tid*16+j)
  const int srow = tid >> 4, scolb = (tid & 15) * 32;
  const int sa0 = srow * 512 + (scolb ^ ((srow & 7) << 4));
  const int sa1 = srow * 512 + ((scolb + 16) ^ ((srow & 7) << 4));
  const int xoff = hi * 1024 + col * 4;

  // zero h0[-1] (h0b[0]) and both h1 buffers (h1[-1] = h1b[0])
  { u32* z0 = (u32*)h0b[0];
    for (int i = tid; i < 4096; i += 512) z0[i] = 0;
    u32* z1 = (u32*)h1b;
    for (int i = tid; i < 8192; i += 512) z1[i] = 0; }

  f32x4 xc0, xc1, xc2, xc3, xn0, xn1, xn2, xn3;
  { const float* p0 = xp + xoff;
    xc0 = *(const f32x4*)(p0);
    xc1 = *(const f32x4*)(p0 + 2048);
    xc2 = *(const f32x4*)(p0 + 4096);
    xc3 = *(const f32x4*)(p0 + 6144); }
  __syncthreads();

#define SIGPACK(WB, ACC)                                                        \
    _Pragma("unroll")                                                           \
    for (int q = 0; q < 4; ++q){                                                \
      *(u16*)((WB) + q * 4096 + wa[0]) = f2bf(sigm_fast(ACC[q * 4 + 0]));       \
      *(u16*)((WB) + q * 4096 + wa[1]) = f2bf(sigm_fast(ACC[q * 4 + 1]));       \
      *(u16*)((WB) + q * 4096 + wa[2]) = f2bf(sigm_fast(ACC[q * 4 + 2]));       \
      *(u16*)((WB) + q * 4096 + wa[3]) = f2bf(sigm_fast(ACC[q * 4 + 3]));       \
    }

#define STEP(PAR, S, X0v,X1v,X2v,X3v, Y0v,Y1v,Y2v,Y3v)                          \
  {                                                                             \
    const char* rb0 = (const char*)h0b[PAR];                                    \
    const char* rb1 = (const char*)h1b[1 - (PAR)];                              \
    b16x8 whA[8];                                                               \
    _Pragma("unroll")                                                           \
    for (int ks = 0; ks < 8; ++ks)                                              \
      whA[ks] = *(const b16x8*)(wh1p + ks * 16);                                \
    if ((S) >= 2){                                                              \
      b16x8 v0 = *(const b16x8*)(rb1 + sa0);                                    \
      b16x8 v1 = *(const b16x8*)(rb1 + sa1);                                    \
      u16* hs = outseq + (size_t)((S) - 2) * 8192 + tid * 16;                   \
      *(b16x8*)(hs)     = v0;                                                   \
      *(b16x8*)(hs + 8) = v1;                                                   \
    }                                                                           \
    f32x16 c, d;                                                                \
    _Pragma("unroll")                                                           \
    for (int r = 0; r < 4; ++r){                                                \
      c[r] = X0v[r]; c[4 + r] = X1v[r]; c[8 + r] = X2v[r]; c[12 + r] = X3v[r];  \
    }                                                                           \
    _Pragma("unroll")                                                           \
    for (int r = 0; r < 16; ++r) d[r] = b1;                                     \
    _Pragma("unroll")                                                           \
    for (int k = 0; k < 16; ++k){                                               \
      b16x8 a = *(const b16x8*)(rb0 + base4[k & 3] + (k >> 2) * 128);           \
      c = __builtin_amdgcn_mfma_f32_32x32x16_bf16(a, wH0[k], c, 0, 0, 0);       \
      d = __builtin_amdgcn_mfma_f32_32x32x16_bf16(a, wI1[k], d, 0, 0, 0);       \
    }                                                                           \
    { const float* pn = xp + (size_t)(((S) < 255) ? (S) + 1 : 255) * 8192 + xoff; \
      Y0v = *(const f32x4*)(pn);                                                \
      Y1v = *(const f32x4*)(pn + 2048);                                         \
      Y2v = *(const f32x4*)(pn + 4096);                                         \
      Y3v = *(const f32x4*)(pn + 6144); }                                       \
    { char* wb0 = (char*)h0b[1 - (PAR)];                                        \
      SIGPACK(wb0, c) }                                                         \
    b16x8 whB[8];                                                               \
    _Pragma("unroll")                                                           \
    for (int ks = 0; ks < 8; ++ks)                                              \
      whB[ks] = *(const b16x8*)(wh1p + 128 + ks * 16);                          \
    if ((S) >= 1){                                                              \
      _Pragma("unroll")                                                         \
      for (int k = 0; k < 8; ++k){                                              \
        b16x8 a = *(const b16x8*)(rb1 + base4[k & 3] + (k >> 2) * 128);         \
        d = __builtin_amdgcn_mfma_f32_32x32x16_bf16(a, whA[k], d, 0, 0, 0);     \
      }                                                                         \
      _Pragma("unroll")                                                         \
      for (int k = 8; k < 16; ++k){                                             \
        b16x8 a = *(const b16x8*)(rb1 + base4[k & 3] + (k >> 2) * 128);         \
        d = __builtin_amdgcn_mfma_f32_32x32x16_bf16(a, whB[k - 8], d, 0, 0, 0); \
      }                                                                         \
      char* wb1 = (char*)h1b[PAR];                                              \
      SIGPACK(wb1, d)                                                           \
    }                                                                           \
    __syncthreads();                                                            \
  }

  for (int s2 = 0; s2 < 128; ++s2){
    const int s = s2 * 2;
    STEP(0, s,     xc0,xc1,xc2,xc3, xn0,xn1,xn2,xn3)
    STEP(1, s + 1, xn0,xn1,xn2,xn3, xc0,xc1,xc2,xc3)
  }
#undef STEP

  // --- epilogue: h0[255] in h0b[0]; h1[254] in h1b[1]; compute h1[255] ---
  {
    const char* rb1 = (const char*)h1b[1];
    b16x8 v0 = *(const b16x8*)(rb1 + sa0);
    b16x8 v1 = *(const b16x8*)(rb1 + sa1);
    u16* hs = outseq + (size_t)254 * 8192 + tid * 16;
    *(b16x8*)(hs)     = v0;
    *(b16x8*)(hs + 8) = v1;

    const char* rb0 = (const char*)h0b[0];
    f32x16 d;
    #pragma unroll
    for (int r = 0; r < 16; ++r) d[r] = b1;
    #pragma unroll
    for (int k = 0; k < 16; ++k){
      b16x8 a  = *(const b16x8*)(rb0 + base4[k & 3] + (k >> 2) * 128);
      b16x8 a2 = *(const b16x8*)(rb1 + base4[k & 3] + (k >> 2) * 128);
      b16x8 wb = *(const b16x8*)(wh1p + k * 16);
      d = __builtin_amdgcn_mfma_f32_32x32x16_bf16(a,  wI1[k], d, 0, 0, 0);
      d = __builtin_amdgcn_mfma_f32_32x32x16_bf16(a2, wb,     d, 0, 0, 0);
    }
    char* wb1 = (char*)h1b[0];
    SIGPACK(wb1, d)
    __syncthreads();

    const char* f0 = (const char*)h0b[0];
    const char* f1 = (const char*)h1b[0];
    b16x8 a0 = *(const b16x8*)(f0 + sa0), a1 = *(const b16x8*)(f0 + sa1);
    b16x8 c0 = *(const b16x8*)(f1 + sa0), c1 = *(const b16x8*)(f1 + sa1);
    u16* hs2 = outseq + (size_t)255 * 8192 + tid * 16;
    *(b16x8*)(hs2)     = c0;
    *(b16x8*)(hs2 + 8) = c1;
    float* hd0 = hid + tid * 16;
    float* hd1 = hid + 8192 + tid * 16;
    #pragma unroll
    for (int j = 0; j < 8; ++j){
      hd0[j]     = bf2f(a0[j]);
      hd0[8 + j] = bf2f(a1[j]);
      hd1[j]     = bf2f(c0[j]);
      hd1[8 + j] = bf2f(c1[j]);
    }
  }
#undef SIGPACK
}

// ---------------------------------------------------------------------------
// decoder: decoded[8192][32000] = outseq @ decW^T + decB   (unchanged)
// ---------------------------------------------------------------------------
__global__ __launch_bounds__(512, 1)
void dec_kernel(const u16* __restrict__ A, const u16* __restrict__ Bw,
                const float* __restrict__ decB, float* __restrict__ out){
  __shared__ u16 sA[2][256 * 64];
  __shared__ u16 sB[2][256 * 64];
  const int tid = threadIdx.x, w = tid >> 6, l = tid & 63;
  const int la = l & 31, hi = l >> 5;
  const int wm = w >> 2, wn = w & 3;

  const int bid = blockIdx.x;
  const int sb  = (bid & 7) * 500 + (bid >> 3);
  const int mb  = sb & 31;
  const int nb  = sb >> 5;

  const int srow = tid >> 3;
  const int sc   = tid & 7;
  const int scx  = sc ^ (srow & 7);
  const size_t gA = ((size_t)(mb * 256 + srow)) * H_ + sc * 8;
  const size_t gB = ((size_t)(nb * 256 + srow)) * H_ + sc * 8;
  const int    sl = srow * 128 + scx * 16;

  b16x8 rA[4], rB[4];
#define GLOADS(KK)                                                              \
  { _Pragma("unroll")                                                           \
    for (int s = 0; s < 4; ++s){                                                \
      rA[s] = *(const b16x8*)(A  + gA + (size_t)s * 64 * H_ + (KK) * 64);       \
      rB[s] = *(const b16x8*)(Bw + gB + (size_t)s * 64 * H_ + (KK) * 64);       \
    } }
#define DSWRITE(BUF)                                                            \
  { _Pragma("unroll")                                                           \
    for (int s = 0; s < 4; ++s){                                                \
      *(b16x8*)((char*)sA[BUF] + s * 8192 + sl) = rA[s];                        \
      *(b16x8*)((char*)sB[BUF] + s * 8192 + sl) = rB[s];                        \
    } }

  const int aRow = wm * 128 + la;
  const int bRow = wn * 64 + la;
  int fOff[4];
  #pragma unroll
  for (int ks = 0; ks < 4; ++ks)
    fOff[ks] = ((ks * 32 + hi * 16) ^ ((la & 7) << 4));

  f32x16 acc[4][2];
  #pragma unroll
  for (int mt = 0; mt < 4; ++mt)
    #pragma unroll
    for (int nt = 0; nt < 2; ++nt)
      acc[mt][nt] = (f32x16){};

  GLOADS(0);
  #pragma unroll
  for (int kk = 0; kk < 4; ++kk){
    DSWRITE(kk & 1);
    if (kk < 3) GLOADS(kk + 1);
    __syncthreads();
    const char* bufA = (const char*)sA[kk & 1];
    const char* bufB = (const char*)sB[kk & 1];
    #pragma unroll
    for (int ks = 0; ks < 4; ++ks){
      b16x8 aF[4], bF[2];
      #pragma unroll
      for (int mt = 0; mt < 4; ++mt)
        aF[mt] = *(const b16x8*)(bufA + (aRow + mt * 32) * 128 + fOff[ks]);
      #pragma unroll
      for (int nt = 0; nt < 2; ++nt)
        bF[nt] = *(const b16x8*)(bufB + (bRow + nt * 32) * 128 + fOff[ks]);
      #pragma unroll
      for (int mt = 0; mt < 4; ++mt)
        #pragma unroll
        for (int nt = 0; nt < 2; ++nt)
          acc[mt][nt] = __builtin_amdgcn_mfma_f32_32x32x16_bf16(aF[mt], bF[nt], acc[mt][nt], 0, 0, 0);
    }
    __syncthreads();
  }
#undef GLOADS
#undef DSWRITE

  #pragma unroll
  for (int nt = 0; nt < 2; ++nt){
    const int colg = nb * 256 + wn * 64 + nt * 32 + la;
    const float bias = decB[colg];
    #pragma unroll
    for (int mt = 0; mt < 4; ++mt){
      const int rowb = mb * 256 + wm * 128 + mt * 32 + hi * 4;
      #pragma unroll
      for (int r = 0; r < 16; ++r){
        const int rowg = rowb + (r & 3) + 8 * (r >> 2);
        out[(size_t)rowg * V_ + colg] = acc[mt][nt][r] + bias;
      }
    }
  }
}

// ---------------------------------------------------------------------------
extern "C" void kernel_launch(void* const* d_in, const int* in_sizes, int n_in,
                              void* d_out, int out_size, void* d_ws, size_t ws_size,
                              hipStream_t stream){
  const int*   ids  = (const int*)  d_in[0];
  const float* emb  = (const float*)d_in[1];
  const float* Wi   = (const float*)d_in[2];
  const float* Wh   = (const float*)d_in[3];
  const float* bh   = (const float*)d_in[4];
  const float* decW = (const float*)d_in[5];
  const float* decB = (const float*)d_in[6];
  float* out = (float*)d_out;

  char* ws = (char*)d_ws;
  u16*  decWb  = (u16*)(ws);                       // 16,384,000 B
  u16*  wt     = (u16*)(ws + 16384000);            //    524,288 B
  u16*  outseq = (u16*)(ws + 16908288);            //  4,194,304 B
  float* xp    = (float*)(ws + 21102592);          //  8,388,608 B

  float* hid = out + (size_t)T_ * B_ * V_;         // [L][B][H] fp32 tail of d_out

  prep_kernel<<<2048, 256, 0, stream>>>(Wi, Wh, decW, decWb, wt);
  x0_kernel<<<256, 512, 0, stream>>>(ids, emb, wt + 3 * H_ * H_, bh, xp);
  fused_rec<<<1, 512, 0, stream>>>(wt, xp, bh, outseq, hid);
  dec_kernel<<<4000, 512, 0, stream>>>(outseq, decWb, decB, out);
}

// Round 7
// 722.275 us; speedup vs baseline: 1.8019x; 1.8019x over previous
//
#include <hip/hip_runtime.h>

typedef unsigned short u16;
typedef unsigned int   u32;
typedef __attribute__((ext_vector_type(4)))  float f32x4;
typedef __attribute__((ext_vector_type(16))) float f32x16;
typedef __attribute__((ext_vector_type(8)))  short b16x8;

#define T_ 256
#define B_ 32
#define V_ 32000
#define H_ 256

// fp32 -> bf16 round-to-nearest-even
__device__ __forceinline__ u16 f2bf(float f){
  union { float fv; u32 uv; } v; v.fv = f;
  return (u16)((v.uv + 0x7FFFu + ((v.uv >> 16) & 1u)) >> 16);
}
__device__ __forceinline__ float bf2f(short x){
  union { float fv; u32 uv; } c; c.uv = ((u32)(u16)x) << 16; return c.fv;
}
__device__ __forceinline__ float sigm_fast(float z){
  return __builtin_amdgcn_rcpf(1.0f + __builtin_amdgcn_exp2f(z * -1.44269504f));
}

// ---------------------------------------------------------------------------
// prep: decW -> bf16 ; W^T bf16 copies (WhT0, WiT1, WhT1, WiT0)
// wt[m][j][k] = W_m[k][j]
// ---------------------------------------------------------------------------
__global__ __launch_bounds__(256)
void prep_kernel(const float* __restrict__ Wi, const float* __restrict__ Wh,
                 const float* __restrict__ decW,
                 u16* __restrict__ decWb, u16* __restrict__ wt){
  const int NDEC = V_ * H_;
  const int NWT  = 4 * H_ * H_;
  const int total = NDEC + NWT;
  for (int i = blockIdx.x * blockDim.x + threadIdx.x; i < total;
       i += gridDim.x * blockDim.x){
    if (i < NDEC){
      decWb[i] = f2bf(decW[i]);
    } else {
      int j = i - NDEC;
      int m = j >> 16;
      int r = j & 65535;
      int row = r >> 8;
      int k   = r & 255;
      const float* src = (m == 0) ? Wh
                       : (m == 1) ? (Wi + H_ * H_)
                       : (m == 2) ? (Wh + H_ * H_)
                       :            Wi;
      wt[j] = f2bf(src[k * H_ + row]);
    }
  }
}

// xp permuted layout for the 16-row M=16 consumer:
//   x[t][bid*16 + lh*4 + rr][col]  ->  xp[t*8192 + bid*4096 + lh*1024 + col*4 + rr]

// ---------------------------------------------------------------------------
// x0[t][b][j] = bh0[j] + emb[ids[t,b]] @ Wi0   (permuted store)
// ---------------------------------------------------------------------------
__global__ __launch_bounds__(512, 2)
void x0_kernel(const int* __restrict__ ids, const float* __restrict__ emb,
               const u16* __restrict__ WiT0, const float* __restrict__ bh,
               float* __restrict__ xp){
  const int tid = threadIdx.x, w = tid >> 6, l = tid & 63, lr = l & 15, lh = l >> 4;
  const int mb = blockIdx.x >> 2;
  const int nb = blockIdx.x & 3;
  const int arow = mb * 128 + w * 16 + lr;
  const int id = ids[arow];
  const float* erow = emb + (size_t)id * H_;

  f32x4 acc[4];
  #pragma unroll
  for (int nt = 0; nt < 4; ++nt){
    float b0 = bh[nb * 64 + nt * 16 + lr];
    acc[nt] = (f32x4){b0, b0, b0, b0};
  }
  #pragma unroll
  for (int ks = 0; ks < 8; ++ks){
    const float* ap = erow + ks * 32 + lh * 8;
    f32x4 e0 = *(const f32x4*)(ap);
    f32x4 e1 = *(const f32x4*)(ap + 4);
    b16x8 a;
    #pragma unroll
    for (int i2 = 0; i2 < 4; ++i2){
      a[i2]     = (short)f2bf(e0[i2]);
      a[4 + i2] = (short)f2bf(e1[i2]);
    }
    #pragma unroll
    for (int nt = 0; nt < 4; ++nt){
      b16x8 b = *(const b16x8*)(WiT0 + (size_t)(nb * 64 + nt * 16 + lr) * H_ + ks * 32 + lh * 8);
      acc[nt] = __builtin_amdgcn_mfma_f32_16x16x32_bf16(a, b, acc[nt], 0, 0, 0);
    }
  }
  // row gr = mb*128 + w*16 + lh*4 + rr  ->  t = gr>>5, b = (w&1)*16 + lh*4 + rr
  const int t    = mb * 4 + (w >> 1);
  const int bid2 = w & 1;
  #pragma unroll
  for (int nt = 0; nt < 4; ++nt){
    const int col = nb * 64 + nt * 16 + lr;
    *(f32x4*)(xp + (size_t)t * 8192 + bid2 * 4096 + lh * 1024 + col * 4) = acc[nt];
  }
}

// ---------------------------------------------------------------------------
// fused_rec16: both layers, batch-split. Block bid owns rows [bid*16, +16).
// 8 waves, 16x16x32 MFMA; wave w owns cols [w*32, w*32+32) (nt = 0,1).
// ALL weights persistent in registers (192 VGPR). Skewed schedule
// (round-6-verified): step s computes h0[s] and h1[s-1]; 1 barrier/step.
//   h0[u] lives in h0b[(u+1)&1]; h1[u] lives in h1b[(u+1)&1].
// LDS tile 16x256 bf16: byte(row,col) = row*512 + ((col*2) ^ ((row&7)<<4))
// ---------------------------------------------------------------------------
__global__ __launch_bounds__(512, 1)
void fused_rec16(const u16* __restrict__ wt, const float* __restrict__ xp,
                 const float* __restrict__ bh,
                 u16* __restrict__ outseq, float* __restrict__ hid){
  __shared__ u16 h0b[2][16 * H_];                    // 2 x 8 KiB
  __shared__ u16 h1b[2][16 * H_];                    // 2 x 8 KiB
  const int tid = threadIdx.x, w = tid >> 6, l = tid & 63;
  const int lr = l & 15, lh = l >> 4;
  const int bid = blockIdx.x;

  const u16* whT0 = wt;
  const u16* wiT1 = wt + 65536;
  const u16* whT1 = wt + 131072;

  // persistent weight fragments [nt][ks]
  b16x8 wH0[2][8], wI1[2][8], wH1[2][8];
  #pragma unroll
  for (int nt = 0; nt < 2; ++nt){
    const int col = w * 32 + nt * 16 + lr;
    #pragma unroll
    for (int ks = 0; ks < 8; ++ks){
      wH0[nt][ks] = *(const b16x8*)(whT0 + (size_t)col * H_ + ks * 32 + lh * 8);
      wI1[nt][ks] = *(const b16x8*)(wiT1 + (size_t)col * H_ + ks * 32 + lh * 8);
      wH1[nt][ks] = *(const b16x8*)(whT1 + (size_t)col * H_ + ks * 32 + lh * 8);
    }
  }
  const float b1a = bh[H_ + w * 32 + lr];
  const float b1b = bh[H_ + w * 32 + 16 + lr];

  // A-read offsets (row = lr)
  int ra[8];
  #pragma unroll
  for (int ks = 0; ks < 8; ++ks)
    ra[ks] = lr * 512 + ((ks * 64 + lh * 16) ^ ((lr & 7) << 4));

  // h-write byte addrs [nt][rr]: row = lh*4+rr
  int wa[2][4];
  #pragma unroll
  for (int nt = 0; nt < 2; ++nt)
    #pragma unroll
    for (int rr = 0; rr < 4; ++rr){
      const int row = lh * 4 + rr;
      wa[nt][rr] = row * 512 + (((w * 32 + nt * 16 + lr) * 2) ^ ((row & 7) << 4));
    }

  // linear store-read (16 B/thread): row = tid>>5
  const int srow = tid >> 5, scolb = (tid & 31) * 16;
  const int sa = srow * 512 + (scolb ^ ((srow & 7) << 4));
  const size_t sgbase = (size_t)(bid * 16 + srow) * H_ + (tid & 31) * 8;

  const int xoff = bid * 4096 + lh * 1024 + (w * 32 + lr) * 4;

  // zero h0[-1] (h0b[0]) and both h1 buffers
  { u32* z0 = (u32*)h0b[0];
    for (int i = tid; i < 2048; i += 512) z0[i] = 0;
    u32* z1 = (u32*)h1b;
    for (int i = tid; i < 4096; i += 512) z1[i] = 0; }

  f32x4 xc0, xc1, xn0, xn1;
  xc0 = *(const f32x4*)(xp + xoff);
  xc1 = *(const f32x4*)(xp + xoff + 64);
  __syncthreads();

#define STEP(PAR, S)                                                            \
  {                                                                             \
    const char* rb0 = (const char*)h0b[PAR];                                    \
    const char* rb1 = (const char*)h1b[1 - (PAR)];                              \
    if ((S) >= 2){                                                              \
      b16x8 v = *(const b16x8*)(rb1 + sa);                                      \
      *(b16x8*)(outseq + (size_t)((S) - 2) * 8192 + sgbase) = v;                \
    }                                                                           \
    f32x4 c0 = xc0, c1 = xc1;                                                   \
    f32x4 d0 = (f32x4){b1a, b1a, b1a, b1a};                                     \
    f32x4 d1 = (f32x4){b1b, b1b, b1b, b1b};                                     \
    _Pragma("unroll")                                                           \
    for (int ks = 0; ks < 8; ++ks){                                             \
      b16x8 a = *(const b16x8*)(rb0 + ra[ks]);                                  \
      c0 = __builtin_amdgcn_mfma_f32_16x16x32_bf16(a, wH0[0][ks], c0, 0, 0, 0); \
      c1 = __builtin_amdgcn_mfma_f32_16x16x32_bf16(a, wH0[1][ks], c1, 0, 0, 0); \
      d0 = __builtin_amdgcn_mfma_f32_16x16x32_bf16(a, wI1[0][ks], d0, 0, 0, 0); \
      d1 = __builtin_amdgcn_mfma_f32_16x16x32_bf16(a, wI1[1][ks], d1, 0, 0, 0); \
    }                                                                           \
    { const float* pn = xp + (size_t)(((S) < 255) ? (S) + 1 : 255) * 8192 + xoff; \
      xn0 = *(const f32x4*)(pn);                                                \
      xn1 = *(const f32x4*)(pn + 64); }                                         \
    { char* wb0 = (char*)h0b[1 - (PAR)];                                        \
      _Pragma("unroll")                                                         \
      for (int rr = 0; rr < 4; ++rr){                                           \
        *(u16*)(wb0 + wa[0][rr]) = f2bf(sigm_fast(c0[rr]));                     \
        *(u16*)(wb0 + wa[1][rr]) = f2bf(sigm_fast(c1[rr]));                     \
      }                                                                         \
    }                                                                           \
    if ((S) >= 1){                                                              \
      _Pragma("unroll")                                                         \
      for (int ks = 0; ks < 8; ++ks){                                           \
        b16x8 a = *(const b16x8*)(rb1 + ra[ks]);                                \
        d0 = __builtin_amdgcn_mfma_f32_16x16x32_bf16(a, wH1[0][ks], d0, 0, 0, 0); \
        d1 = __builtin_amdgcn_mfma_f32_16x16x32_bf16(a, wH1[1][ks], d1, 0, 0, 0); \
      }                                                                         \
      char* wb1 = (char*)h1b[PAR];                                              \
      _Pragma("unroll")                                                         \
      for (int rr = 0; rr < 4; ++rr){                                           \
        *(u16*)(wb1 + wa[0][rr]) = f2bf(sigm_fast(d0[rr]));                     \
        *(u16*)(wb1 + wa[1][rr]) = f2bf(sigm_fast(d1[rr]));                     \
      }                                                                         \
    }                                                                           \
    xc0 = xn0; xc1 = xn1;                                                       \
    __syncthreads();                                                            \
  }

  for (int s2 = 0; s2 < 128; ++s2){
    const int s = s2 * 2;
    STEP(0, s)
    STEP(1, s + 1)
  }
#undef STEP

  // epilogue: h0[255] in h0b[0]; h1[254] in h1b[1]; compute h1[255]
  {
    const char* rb0 = (const char*)h0b[0];
    const char* rb1 = (const char*)h1b[1];
    { b16x8 v = *(const b16x8*)(rb1 + sa);
      *(b16x8*)(outseq + (size_t)254 * 8192 + sgbase) = v; }

    f32x4 d0 = (f32x4){b1a, b1a, b1a, b1a};
    f32x4 d1 = (f32x4){b1b, b1b, b1b, b1b};
    #pragma unroll
    for (int ks = 0; ks < 8; ++ks){
      b16x8 a  = *(const b16x8*)(rb0 + ra[ks]);
      b16x8 a2 = *(const b16x8*)(rb1 + ra[ks]);
      d0 = __builtin_amdgcn_mfma_f32_16x16x32_bf16(a,  wI1[0][ks], d0, 0, 0, 0);
      d1 = __builtin_amdgcn_mfma_f32_16x16x32_bf16(a,  wI1[1][ks], d1, 0, 0, 0);
      d0 = __builtin_amdgcn_mfma_f32_16x16x32_bf16(a2, wH1[0][ks], d0, 0, 0, 0);
      d1 = __builtin_amdgcn_mfma_f32_16x16x32_bf16(a2, wH1[1][ks], d1, 0, 0, 0);
    }
    char* wb1 = (char*)h1b[0];
    #pragma unroll
    for (int rr = 0; rr < 4; ++rr){
      *(u16*)(wb1 + wa[0][rr]) = f2bf(sigm_fast(d0[rr]));
      *(u16*)(wb1 + wa[1][rr]) = f2bf(sigm_fast(d1[rr]));
    }
    __syncthreads();

    b16x8 h1v = *(const b16x8*)((const char*)h1b[0] + sa);
    b16x8 h0v = *(const b16x8*)((const char*)h0b[0] + sa);
    *(b16x8*)(outseq + (size_t)255 * 8192 + sgbase) = h1v;
    float* hd0 = hid + sgbase;
    float* hd1 = hid + 8192 + sgbase;
    #pragma unroll
    for (int j = 0; j < 8; ++j){
      hd0[j] = bf2f(h0v[j]);
      hd1[j] = bf2f(h1v[j]);
    }
  }
}

// ---------------------------------------------------------------------------
// decoder: decoded[8192][32000] = outseq @ decW^T + decB   (unchanged)
// ---------------------------------------------------------------------------
__global__ __launch_bounds__(512, 1)
void dec_kernel(const u16* __restrict__ A, const u16* __restrict__ Bw,
                const float* __restrict__ decB, float* __restrict__ out){
  __shared__ u16 sA[2][256 * 64];
  __shared__ u16 sB[2][256 * 64];
  const int tid = threadIdx.x, w = tid >> 6, l = tid & 63;
  const int la = l & 31, hi = l >> 5;
  const int wm = w >> 2, wn = w & 3;

  const int bid = blockIdx.x;
  const int sb  = (bid & 7) * 500 + (bid >> 3);
  const int mb  = sb & 31;
  const int nb  = sb >> 5;

  const int srow = tid >> 3;
  const int sc   = tid & 7;
  const int scx  = sc ^ (srow & 7);
  const size_t gA = ((size_t)(mb * 256 + srow)) * H_ + sc * 8;
  const size_t gB = ((size_t)(nb * 256 + srow)) * H_ + sc * 8;
  const int    sl = srow * 128 + scx * 16;

  b16x8 rA[4], rB[4];
#define GLOADS(KK)                                                              \
  { _Pragma("unroll")                                                           \
    for (int s = 0; s < 4; ++s){                                                \
      rA[s] = *(const b16x8*)(A  + gA + (size_t)s * 64 * H_ + (KK) * 64);       \
      rB[s] = *(const b16x8*)(Bw + gB + (size_t)s * 64 * H_ + (KK) * 64);       \
    } }
#define DSWRITE(BUF)                                                            \
  { _Pragma("unroll")                                                           \
    for (int s = 0; s < 4; ++s){                                                \
      *(b16x8*)((char*)sA[BUF] + s * 8192 + sl) = rA[s];                        \
      *(b16x8*)((char*)sB[BUF] + s * 8192 + sl) = rB[s];                        \
    } }

  const int aRow = wm * 128 + la;
  const int bRow = wn * 64 + la;
  int fOff[4];
  #pragma unroll
  for (int ks = 0; ks < 4; ++ks)
    fOff[ks] = ((ks * 32 + hi * 16) ^ ((la & 7) << 4));

  f32x16 acc[4][2];
  #pragma unroll
  for (int mt = 0; mt < 4; ++mt)
    #pragma unroll
    for (int nt = 0; nt < 2; ++nt)
      acc[mt][nt] = (f32x16){};

  GLOADS(0);
  #pragma unroll
  for (int kk = 0; kk < 4; ++kk){
    DSWRITE(kk & 1);
    if (kk < 3) GLOADS(kk + 1);
    __syncthreads();
    const char* bufA = (const char*)sA[kk & 1];
    const char* bufB = (const char*)sB[kk & 1];
    #pragma unroll
    for (int ks = 0; ks < 4; ++ks){
      b16x8 aF[4], bF[2];
      #pragma unroll
      for (int mt = 0; mt < 4; ++mt)
        aF[mt] = *(const b16x8*)(bufA + (aRow + mt * 32) * 128 + fOff[ks]);
      #pragma unroll
      for (int nt = 0; nt < 2; ++nt)
        bF[nt] = *(const b16x8*)(bufB + (bRow + nt * 32) * 128 + fOff[ks]);
      #pragma unroll
      for (int mt = 0; mt < 4; ++mt)
        #pragma unroll
        for (int nt = 0; nt < 2; ++nt)
          acc[mt][nt] = __builtin_amdgcn_mfma_f32_32x32x16_bf16(aF[mt], bF[nt], acc[mt][nt], 0, 0, 0);
    }
    __syncthreads();
  }
#undef GLOADS
#undef DSWRITE

  #pragma unroll
  for (int nt = 0; nt < 2; ++nt){
    const int colg = nb * 256 + wn * 64 + nt * 32 + la;
    const float bias = decB[colg];
    #pragma unroll
    for (int mt = 0; mt < 4; ++mt){
      const int rowb = mb * 256 + wm * 128 + mt * 32 + hi * 4;
      #pragma unroll
      for (int r = 0; r < 16; ++r){
        const int rowg = rowb + (r & 3) + 8 * (r >> 2);
        out[(size_t)rowg * V_ + colg] = acc[mt][nt][r] + bias;
      }
    }
  }
}

// ---------------------------------------------------------------------------
extern "C" void kernel_launch(void* const* d_in, const int* in_sizes, int n_in,
                              void* d_out, int out_size, void* d_ws, size_t ws_size,
                              hipStream_t stream){
  const int*   ids  = (const int*)  d_in[0];
  const float* emb  = (const float*)d_in[1];
  const float* Wi   = (const float*)d_in[2];
  const float* Wh   = (const float*)d_in[3];
  const float* bh   = (const float*)d_in[4];
  const float* decW = (const float*)d_in[5];
  const float* decB = (const float*)d_in[6];
  float* out = (float*)d_out;

  char* ws = (char*)d_ws;
  u16*  decWb  = (u16*)(ws);                       // 16,384,000 B
  u16*  wt     = (u16*)(ws + 16384000);            //    524,288 B
  u16*  outseq = (u16*)(ws + 16908288);            //  4,194,304 B
  float* xp    = (float*)(ws + 21102592);          //  8,388,608 B

  float* hid = out + (size_t)T_ * B_ * V_;         // [L][B][H] fp32 tail of d_out

  prep_kernel<<<2048, 256, 0, stream>>>(Wi, Wh, decW, decWb, wt);
  x0_kernel<<<256, 512, 0, stream>>>(ids, emb, wt + 3 * H_ * H_, bh, xp);
  fused_rec16<<<2, 512, 0, stream>>>(wt, xp, bh, outseq, hid);
  dec_kernel<<<4000, 512, 0, stream>>>(outseq, decWb, decB, out);
}